// Round 5
// baseline (84.302 us; speedup 1.0000x reference)
//
#include <hip/hip_runtime.h>
#include <hip/hip_bf16.h>

#define B_ 32
#define N_ 4096
#define C_ 256
#define W_ 64
#define OUT_ 512
#define EPS_ 1e-5f

typedef __attribute__((ext_vector_type(8))) short short8;
typedef __attribute__((ext_vector_type(4))) float floatx4;

// workspace layout (bytes)
#define WT_OFF     0                    // wt bf16 [b][w][n] = 16 MB
#define SLABB_OFF  16777216             // 16 slabs bf16 [ks][b][c*64+w] = 16 MB
#define AGGB_OFF   33554432             // aggB bf16 [b][k=c*64+w] = 1 MB
#define PART_OFF   34603008             // k3 partials f32 [kb<64][o*32+b] = 4 MB
#define WS_NEEDED  38797312

__device__ __forceinline__ ushort f2bf(float f) {
  unsigned u = __builtin_bit_cast(unsigned, f);
  unsigned r = (u + 0x7fffu + ((u >> 16) & 1u)) >> 16;  // RTNE
  return (ushort)r;
}
__device__ __forceinline__ unsigned pk2(float a, float b) {
  return (unsigned)f2bf(a) | ((unsigned)f2bf(b) << 16);
}
__device__ __forceinline__ float bflo(unsigned u) {
  return __builtin_bit_cast(float, u << 16);
}
__device__ __forceinline__ float bfhi(unsigned u) {
  return __builtin_bit_cast(float, u & 0xffff0000u);
}

// ---------------- K1: fuse BN + WeightNet (layer1 scalar, layers 2/3 MFMA) ----------------
__global__ __launch_bounds__(256) void k1_weightnet(
    const float* __restrict__ xyz,
    const float* __restrict__ w1, const float* __restrict__ b1,
    const float* __restrict__ g1, const float* __restrict__ be1,
    const float* __restrict__ m1, const float* __restrict__ v1,
    const float* __restrict__ w2, const float* __restrict__ b2,
    const float* __restrict__ g2, const float* __restrict__ be2,
    const float* __restrict__ m2, const float* __restrict__ v2,
    const float* __restrict__ w3, const float* __restrict__ b3,
    const float* __restrict__ g3, const float* __restrict__ be3,
    const float* __restrict__ m3, const float* __restrict__ v3,
    ushort* __restrict__ wt) {
  __shared__ __align__(16) ushort h_lds[256 * 72];   // reused as T[64][132] u32
  __shared__ __align__(16) ushort w2_lds[64 * 72];
  __shared__ __align__(16) ushort w3_lds[64 * 72];
  __shared__ float w1l[192];
  __shared__ float b1l[64];
  __shared__ float b2_lds[64];
  __shared__ float b3_lds[64];

  const int t = threadIdx.x;
  const int blk = blockIdx.x;
  const int b = blk >> 4;
  const int n0 = (blk & 15) << 8;

  if (t < 64) {
    float s1 = g1[t] * rsqrtf(v1[t] + EPS_);
#pragma unroll
    for (int j = 0; j < 3; ++j) w1l[t * 3 + j] = w1[t * 3 + j] * s1;
    b1l[t] = (b1[t] - m1[t]) * s1 + be1[t];

    float s2 = g2[t] * rsqrtf(v2[t] + EPS_);
    unsigned* w2row = (unsigned*)&w2_lds[t * 72];
#pragma unroll
    for (int q = 0; q < 16; ++q) {
      float4 v = *(const float4*)&w2[t * 64 + q * 4];
      w2row[q * 2] = pk2(v.x * s2, v.y * s2);
      w2row[q * 2 + 1] = pk2(v.z * s2, v.w * s2);
    }
    w2row[32] = 0; w2row[33] = 0; w2row[34] = 0; w2row[35] = 0;
    b2_lds[t] = (b2[t] - m2[t]) * s2 + be2[t];

    float s3 = g3[t] * rsqrtf(v3[t] + EPS_);
    unsigned* w3row = (unsigned*)&w3_lds[t * 72];
#pragma unroll
    for (int q = 0; q < 16; ++q) {
      float4 v = *(const float4*)&w3[t * 64 + q * 4];
      w3row[q * 2] = pk2(v.x * s3, v.y * s3);
      w3row[q * 2 + 1] = pk2(v.z * s3, v.w * s3);
    }
    w3row[32] = 0; w3row[33] = 0; w3row[34] = 0; w3row[35] = 0;
    b3_lds[t] = (b3[t] - m3[t]) * s3 + be3[t];
  }
  __syncthreads();

  const int n = n0 + t;
  const float* xp = xyz + ((size_t)b * N_ + n) * 3;
  float x0 = xp[0], x1 = xp[1], x2 = xp[2];
  unsigned* hrow = (unsigned*)&h_lds[t * 72];
#pragma unroll 4
  for (int cp = 0; cp < 32; ++cp) {
    int c0 = cp * 2, c1 = cp * 2 + 1;
    float a0 = fmaxf(b1l[c0] + w1l[c0 * 3] * x0 + w1l[c0 * 3 + 1] * x1 + w1l[c0 * 3 + 2] * x2, 0.f);
    float a1 = fmaxf(b1l[c1] + w1l[c1 * 3] * x0 + w1l[c1 * 3 + 1] * x1 + w1l[c1 * 3 + 2] * x2, 0.f);
    hrow[cp] = pk2(a0, a1);
  }
  __syncthreads();

  const int wv = t >> 6, lane = t & 63;
  const int lrow = lane & 15, lk = lane >> 4;

  floatx4 acc[4][4];
#pragma unroll
  for (int mt = 0; mt < 4; ++mt)
#pragma unroll
    for (int nt = 0; nt < 4; ++nt) acc[mt][nt] = (floatx4){0.f, 0.f, 0.f, 0.f};

#pragma unroll
  for (int ks = 0; ks < 2; ++ks) {
    short8 afr[4], bfr[4];
#pragma unroll
    for (int mt = 0; mt < 4; ++mt)
      afr[mt] = *(const short8*)&h_lds[(wv * 64 + mt * 16 + lrow) * 72 + ks * 32 + lk * 8];
#pragma unroll
    for (int nt = 0; nt < 4; ++nt)
      bfr[nt] = *(const short8*)&w2_lds[(nt * 16 + lrow) * 72 + ks * 32 + lk * 8];
#pragma unroll
    for (int mt = 0; mt < 4; ++mt)
#pragma unroll
      for (int nt = 0; nt < 4; ++nt)
        acc[mt][nt] = __builtin_amdgcn_mfma_f32_16x16x32_bf16(afr[mt], bfr[nt], acc[mt][nt], 0, 0, 0);
  }
#pragma unroll
  for (int mt = 0; mt < 4; ++mt)
#pragma unroll
    for (int nt = 0; nt < 4; ++nt) {
      float bias = b2_lds[nt * 16 + lrow];
#pragma unroll
      for (int r = 0; r < 4; ++r) {
        float v = fmaxf(acc[mt][nt][r] + bias, 0.f);
        h_lds[(wv * 64 + mt * 16 + lk * 4 + r) * 72 + nt * 16 + lrow] = f2bf(v);
      }
    }

  floatx4 acc3[4][4];
#pragma unroll
  for (int mt = 0; mt < 4; ++mt)
#pragma unroll
    for (int nt = 0; nt < 4; ++nt) acc3[mt][nt] = (floatx4){0.f, 0.f, 0.f, 0.f};

#pragma unroll
  for (int ks = 0; ks < 2; ++ks) {
    short8 afr[4], bfr[4];
#pragma unroll
    for (int mt = 0; mt < 4; ++mt)
      afr[mt] = *(const short8*)&h_lds[(wv * 64 + mt * 16 + lrow) * 72 + ks * 32 + lk * 8];
#pragma unroll
    for (int nt = 0; nt < 4; ++nt)
      bfr[nt] = *(const short8*)&w3_lds[(nt * 16 + lrow) * 72 + ks * 32 + lk * 8];
#pragma unroll
    for (int mt = 0; mt < 4; ++mt)
#pragma unroll
      for (int nt = 0; nt < 4; ++nt)
        acc3[mt][nt] = __builtin_amdgcn_mfma_f32_16x16x32_bf16(afr[mt], bfr[nt], acc3[mt][nt], 0, 0, 0);
  }

  __syncthreads();
  unsigned* T = (unsigned*)h_lds;  // T[64 ch][132 u32]
#pragma unroll
  for (int mt = 0; mt < 4; ++mt)
#pragma unroll
    for (int nt = 0; nt < 4; ++nt) {
      float bias = b3_lds[nt * 16 + lrow];
      float v0 = fmaxf(acc3[mt][nt][0] + bias, 0.f);
      float v1 = fmaxf(acc3[mt][nt][1] + bias, 0.f);
      float v2 = fmaxf(acc3[mt][nt][2] + bias, 0.f);
      float v3 = fmaxf(acc3[mt][nt][3] + bias, 0.f);
      int ch = nt * 16 + lrow;
      int pp = (wv * 64 + mt * 16 + lk * 4) >> 1;
      T[ch * 132 + pp] = pk2(v0, v1);
      T[ch * 132 + pp + 1] = pk2(v2, v3);
    }
  __syncthreads();

  const int ch = t >> 2, q = t & 3;
  unsigned* wtu = (unsigned*)wt;
  size_t obase = ((size_t)(b * W_ + ch)) * (N_ / 2) + (n0 >> 1);
#pragma unroll
  for (int j = 0; j < 8; ++j) {
    int col = q * 4 + j * 16;
    uint4 vv = *(const uint4*)&T[ch * 132 + col];
    *(uint4*)&wtu[obase + col] = vv;
  }
}

// ---------------- K2: slab[ks][b][c*64+w] (bf16) = sum_{k-chunk} feat[b][c][k]/N * wt[b][w][k] ----------------
// 4096 single-wave blocks: blk = (b*8 + ct)*16 + ks. Wave = 32 c x 64 w x 256 k.
// A-operand = wt (w rows), B-operand = feat (c rows) -> D row = w (packable stores).
__global__ __launch_bounds__(64, 2) void k2_agg(const float* __restrict__ feature,
                                                const ushort* __restrict__ wt,
                                                ushort* __restrict__ slabs) {
  const int lane = threadIdx.x;
  const int lrow = lane & 15, lk = lane >> 4;
  const int blk = blockIdx.x;
  const int KS = blk & 15;
  const int CT = (blk >> 4) & 7;   // wt-sharing blocks at blk-stride 16 -> same XCD
  const int b = blk >> 7;

  const float* fA = feature + ((size_t)(b * C_ + CT * 32 + lrow)) * N_ + KS * 256 + lk * 8;
  const float* fB = fA + (size_t)16 * N_;
  const ushort* w0 = wt + ((size_t)(b * W_ + lrow)) * N_ + KS * 256 + lk * 8;

  floatx4 acc[2][4];   // [m: c-group][g: w-group]
#pragma unroll
  for (int m = 0; m < 2; ++m)
#pragma unroll
    for (int g = 0; g < 4; ++g) acc[m][g] = (floatx4){0.f, 0.f, 0.f, 0.f};

  float4 A[4][4];
  short8 Bv[4][4];

#define LOADSTEP(s, kof)                                        \
  do {                                                          \
    A[s][0] = *(const float4*)(fA + (kof));                     \
    A[s][1] = *(const float4*)(fA + (kof) + 4);                 \
    A[s][2] = *(const float4*)(fB + (kof));                     \
    A[s][3] = *(const float4*)(fB + (kof) + 4);                 \
    Bv[s][0] = *(const short8*)(w0 + (kof));                    \
    Bv[s][1] = *(const short8*)(w0 + (kof) + 16 * N_);          \
    Bv[s][2] = *(const short8*)(w0 + (kof) + 32 * N_);          \
    Bv[s][3] = *(const short8*)(w0 + (kof) + 48 * N_);          \
  } while (0)

  LOADSTEP(0, 0);
  LOADSTEP(1, 32);
  LOADSTEP(2, 64);
  LOADSTEP(3, 96);

#pragma unroll
  for (int kk = 0; kk < 8; ++kk) {
    const int st = kk & 3;
    union { unsigned u[4]; short8 s8; } p0, p1;
    p0.u[0] = pk2(A[st][0].x, A[st][0].y);
    p0.u[1] = pk2(A[st][0].z, A[st][0].w);
    p0.u[2] = pk2(A[st][1].x, A[st][1].y);
    p0.u[3] = pk2(A[st][1].z, A[st][1].w);
    p1.u[0] = pk2(A[st][2].x, A[st][2].y);
    p1.u[1] = pk2(A[st][2].z, A[st][2].w);
    p1.u[2] = pk2(A[st][3].x, A[st][3].y);
    p1.u[3] = pk2(A[st][3].z, A[st][3].w);
#pragma unroll
    for (int g = 0; g < 4; ++g)
      acc[0][g] = __builtin_amdgcn_mfma_f32_16x16x32_bf16(Bv[st][g], p0.s8, acc[0][g], 0, 0, 0);
#pragma unroll
    for (int g = 0; g < 4; ++g)
      acc[1][g] = __builtin_amdgcn_mfma_f32_16x16x32_bf16(Bv[st][g], p1.s8, acc[1][g], 0, 0, 0);
    if (kk < 4) LOADSTEP(st, (kk + 4) * 32);
  }
#undef LOADSTEP

  // D: row = w = g*16 + lk*4 + r, col = c = CT*32 + m*16 + lrow -> pack r-pairs along w
  const float sc = 1.f / 4096.f;
  ushort* slab = slabs + ((size_t)(KS * B_ + b)) * 16384;
#pragma unroll
  for (int m = 0; m < 2; ++m)
#pragma unroll
    for (int g = 0; g < 4; ++g) {
      int c = CT * 32 + m * 16 + lrow;
      int w4 = g * 16 + lk * 4;
      uint2 pv;
      pv.x = pk2(acc[m][g][0] * sc, acc[m][g][1] * sc);
      pv.y = pk2(acc[m][g][2] * sc, acc[m][g][3] * sc);
      *(uint2*)&slab[c * 64 + w4] = pv;
    }
}

// ---------------- K2b: aggB[b][k=cw] (bf16) = sum_ks slab[ks][b][cw] ----------------
__global__ __launch_bounds__(256) void k2b_reduce(const ushort* __restrict__ slabs,
                                                  ushort* __restrict__ aggB) {
  const int t = threadIdx.x;
  const int b = blockIdx.x >> 3;
  const int cw = (blockIdx.x & 7) * 2048 + t * 8;

  float s[8] = {0.f, 0.f, 0.f, 0.f, 0.f, 0.f, 0.f, 0.f};
#pragma unroll
  for (int ks = 0; ks < 16; ++ks) {
    const ushort* p = slabs + ((size_t)(ks * B_ + b)) * 16384 + cw;
    uint4 v = *(const uint4*)p;
    s[0] += bflo(v.x); s[1] += bfhi(v.x);
    s[2] += bflo(v.y); s[3] += bfhi(v.y);
    s[4] += bflo(v.z); s[5] += bfhi(v.z);
    s[6] += bflo(v.w); s[7] += bfhi(v.w);
  }
  uint4 o;
  o.x = pk2(s[0], s[1]); o.y = pk2(s[2], s[3]);
  o.z = pk2(s[4], s[5]); o.w = pk2(s[6], s[7]);
  *(uint4*)&aggB[(size_t)b * 16384 + cw] = o;
}

// ---------------- K3: part[kb][o*32+b] = sum_{k-chunk} wf[o][k] * aggB[b][k]  (MFMA) ----------------
// 512 blocks = 8 o-tiles x 64 k-splits, 4 waves; wave owns 16 o rows, all 32 b, 256 k.
__global__ __launch_bounds__(256) void k3_final(const float* __restrict__ wf,
                                                const ushort* __restrict__ aggB,
                                                float* __restrict__ part) {
  const int t = threadIdx.x;
  const int wv = t >> 6, lane = t & 63;
  const int lrow = lane & 15, lk = lane >> 4;
  const int ot = blockIdx.x >> 6;
  const int kb = blockIdx.x & 63;
  const int o0 = ot * 64 + wv * 16;
  const int k0 = kb * 256;

  const float* wp = wf + (size_t)(o0 + lrow) * 16384 + k0 + lk * 8;
  const ushort* a0 = aggB + (size_t)lrow * 16384 + k0 + lk * 8;
  const ushort* a1 = a0 + (size_t)16 * 16384;

  floatx4 acc0 = {0.f, 0.f, 0.f, 0.f}, acc1 = {0.f, 0.f, 0.f, 0.f};
#pragma unroll
  for (int s = 0; s < 8; ++s) {
    float4 f0 = *(const float4*)(wp + s * 32);
    float4 f1 = *(const float4*)(wp + s * 32 + 4);
    short8 b0 = *(const short8*)(a0 + s * 32);
    short8 b1 = *(const short8*)(a1 + s * 32);
    union { unsigned u[4]; short8 s8; } pa;
    pa.u[0] = pk2(f0.x, f0.y);
    pa.u[1] = pk2(f0.z, f0.w);
    pa.u[2] = pk2(f1.x, f1.y);
    pa.u[3] = pk2(f1.z, f1.w);
    acc0 = __builtin_amdgcn_mfma_f32_16x16x32_bf16(pa.s8, b0, acc0, 0, 0, 0);
    acc1 = __builtin_amdgcn_mfma_f32_16x16x32_bf16(pa.s8, b1, acc1, 0, 0, 0);
  }

  // D: row = o = lk*4+r, col = b = lrow (+16 for acc1)
  float* dst = part + (size_t)kb * 16384;
#pragma unroll
  for (int r = 0; r < 4; ++r) {
    int o = o0 + lk * 4 + r;
    dst[o * 32 + lrow] = acc0[r];
    dst[o * 32 + 16 + lrow] = acc1[r];
  }
}

// ---------------- K4: reduce partials + final BN + ReLU ----------------
__global__ void k4_finalize(const float* __restrict__ bf, const float* __restrict__ gf,
                            const float* __restrict__ bef, const float* __restrict__ mf,
                            const float* __restrict__ vf, const float* __restrict__ part,
                            float* __restrict__ out) {
  int i = blockIdx.x * 256 + threadIdx.x;  // 0..16383
  int o = i >> 5, b = i & 31;
  float v = 0.f;
#pragma unroll
  for (int kb = 0; kb < 64; ++kb) v += part[(size_t)kb * 16384 + i];
  float s = gf[o] * rsqrtf(vf[o] + EPS_);
  float r = (v + bf[o] - mf[o]) * s + bef[o];
  out[b * OUT_ + o] = fmaxf(r, 0.f);
}

extern "C" void kernel_launch(void* const* d_in, const int* in_sizes, int n_in,
                              void* d_out, int out_size, void* d_ws, size_t ws_size,
                              hipStream_t stream) {
  const float* xyz     = (const float*)d_in[0];
  const float* feature = (const float*)d_in[1];
  const float* w1 = (const float*)d_in[3];
  const float* b1 = (const float*)d_in[4];
  const float* g1 = (const float*)d_in[5];
  const float* be1 = (const float*)d_in[6];
  const float* m1 = (const float*)d_in[7];
  const float* v1 = (const float*)d_in[8];
  const float* w2 = (const float*)d_in[9];
  const float* b2 = (const float*)d_in[10];
  const float* g2 = (const float*)d_in[11];
  const float* be2 = (const float*)d_in[12];
  const float* m2 = (const float*)d_in[13];
  const float* v2 = (const float*)d_in[14];
  const float* w3 = (const float*)d_in[15];
  const float* b3 = (const float*)d_in[16];
  const float* g3 = (const float*)d_in[17];
  const float* be3 = (const float*)d_in[18];
  const float* m3 = (const float*)d_in[19];
  const float* v3 = (const float*)d_in[20];
  const float* wf = (const float*)d_in[21];
  const float* bf = (const float*)d_in[22];
  const float* gf = (const float*)d_in[23];
  const float* bef = (const float*)d_in[24];
  const float* mf = (const float*)d_in[25];
  const float* vf = (const float*)d_in[26];

  char* ws = (char*)d_ws;
  if (ws_size < (size_t)WS_NEEDED) return;
  ushort* wt    = (ushort*)(ws + WT_OFF);
  ushort* slabs = (ushort*)(ws + SLABB_OFF);
  ushort* aggB  = (ushort*)(ws + AGGB_OFF);
  float*  part  = (float*)(ws + PART_OFF);

  k1_weightnet<<<512, 256, 0, stream>>>(xyz,
                                        w1, b1, g1, be1, m1, v1,
                                        w2, b2, g2, be2, m2, v2,
                                        w3, b3, g3, be3, m3, v3, wt);
  k2_agg<<<4096, 64, 0, stream>>>(feature, wt, slabs);
  k2b_reduce<<<256, 256, 0, stream>>>(slabs, aggB);
  k3_final<<<512, 256, 0, stream>>>(wf, aggB, part);
  k4_finalize<<<64, 256, 0, stream>>>(bf, gf, bef, mf, vf, part, (float*)d_out);
}

// Round 6
// 75.030 us; speedup vs baseline: 1.1236x; 1.1236x over previous
//
#include <hip/hip_runtime.h>
#include <hip/hip_bf16.h>

#define B_ 32
#define N_ 4096
#define C_ 256
#define W_ 64
#define OUT_ 512
#define EPS_ 1e-5f

typedef __attribute__((ext_vector_type(8))) short short8;
typedef __attribute__((ext_vector_type(4))) float floatx4;

// workspace layout (bytes)
#define WT_OFF     0                    // wt bf16 [b][w][n] = 16 MB
#define SLABF_OFF  16777216             // 4 slabs f32 [ks][b][c*64+w] = 8 MB
#define AGGB_OFF   25165824             // aggB bf16 [b][k=c*64+w] = 1 MB
#define PART_OFF   26214400             // k3 partials f32 [kb<64][o*32+b] = 4 MB
#define WS_NEEDED  30408704

#define GLOAD_LDS16(g, l)                                                  \
  __builtin_amdgcn_global_load_lds(                                        \
      (const __attribute__((address_space(1))) void*)(g),                  \
      (__attribute__((address_space(3))) void*)(l), 16, 0, 0)

__device__ __forceinline__ ushort f2bf(float f) {
  unsigned u = __builtin_bit_cast(unsigned, f);
  unsigned r = (u + 0x7fffu + ((u >> 16) & 1u)) >> 16;  // RTNE
  return (ushort)r;
}
__device__ __forceinline__ unsigned pk2(float a, float b) {
  return (unsigned)f2bf(a) | ((unsigned)f2bf(b) << 16);
}

// ---------------- K1: fuse BN + WeightNet (layer1 scalar, layers 2/3 MFMA) ----------------
__global__ __launch_bounds__(256) void k1_weightnet(
    const float* __restrict__ xyz,
    const float* __restrict__ w1, const float* __restrict__ b1,
    const float* __restrict__ g1, const float* __restrict__ be1,
    const float* __restrict__ m1, const float* __restrict__ v1,
    const float* __restrict__ w2, const float* __restrict__ b2,
    const float* __restrict__ g2, const float* __restrict__ be2,
    const float* __restrict__ m2, const float* __restrict__ v2,
    const float* __restrict__ w3, const float* __restrict__ b3,
    const float* __restrict__ g3, const float* __restrict__ be3,
    const float* __restrict__ m3, const float* __restrict__ v3,
    ushort* __restrict__ wt) {
  __shared__ __align__(16) ushort h_lds[256 * 72];   // reused as T[64][132] u32
  __shared__ __align__(16) ushort w2_lds[64 * 72];
  __shared__ __align__(16) ushort w3_lds[64 * 72];
  __shared__ float w1l[192];
  __shared__ float b1l[64];
  __shared__ float b2_lds[64];
  __shared__ float b3_lds[64];

  const int t = threadIdx.x;
  const int blk = blockIdx.x;
  const int b = blk >> 4;
  const int n0 = (blk & 15) << 8;

  if (t < 64) {
    float s1 = g1[t] * rsqrtf(v1[t] + EPS_);
#pragma unroll
    for (int j = 0; j < 3; ++j) w1l[t * 3 + j] = w1[t * 3 + j] * s1;
    b1l[t] = (b1[t] - m1[t]) * s1 + be1[t];

    float s2 = g2[t] * rsqrtf(v2[t] + EPS_);
    unsigned* w2row = (unsigned*)&w2_lds[t * 72];
#pragma unroll
    for (int q = 0; q < 16; ++q) {
      float4 v = *(const float4*)&w2[t * 64 + q * 4];
      w2row[q * 2] = pk2(v.x * s2, v.y * s2);
      w2row[q * 2 + 1] = pk2(v.z * s2, v.w * s2);
    }
    w2row[32] = 0; w2row[33] = 0; w2row[34] = 0; w2row[35] = 0;
    b2_lds[t] = (b2[t] - m2[t]) * s2 + be2[t];

    float s3 = g3[t] * rsqrtf(v3[t] + EPS_);
    unsigned* w3row = (unsigned*)&w3_lds[t * 72];
#pragma unroll
    for (int q = 0; q < 16; ++q) {
      float4 v = *(const float4*)&w3[t * 64 + q * 4];
      w3row[q * 2] = pk2(v.x * s3, v.y * s3);
      w3row[q * 2 + 1] = pk2(v.z * s3, v.w * s3);
    }
    w3row[32] = 0; w3row[33] = 0; w3row[34] = 0; w3row[35] = 0;
    b3_lds[t] = (b3[t] - m3[t]) * s3 + be3[t];
  }
  __syncthreads();

  const int n = n0 + t;
  const float* xp = xyz + ((size_t)b * N_ + n) * 3;
  float x0 = xp[0], x1 = xp[1], x2 = xp[2];
  unsigned* hrow = (unsigned*)&h_lds[t * 72];
#pragma unroll 4
  for (int cp = 0; cp < 32; ++cp) {
    int c0 = cp * 2, c1 = cp * 2 + 1;
    float a0 = fmaxf(b1l[c0] + w1l[c0 * 3] * x0 + w1l[c0 * 3 + 1] * x1 + w1l[c0 * 3 + 2] * x2, 0.f);
    float a1 = fmaxf(b1l[c1] + w1l[c1 * 3] * x0 + w1l[c1 * 3 + 1] * x1 + w1l[c1 * 3 + 2] * x2, 0.f);
    hrow[cp] = pk2(a0, a1);
  }
  __syncthreads();

  const int wv = t >> 6, lane = t & 63;
  const int lrow = lane & 15, lk = lane >> 4;

  floatx4 acc[4][4];
#pragma unroll
  for (int mt = 0; mt < 4; ++mt)
#pragma unroll
    for (int nt = 0; nt < 4; ++nt) acc[mt][nt] = (floatx4){0.f, 0.f, 0.f, 0.f};

#pragma unroll
  for (int ks = 0; ks < 2; ++ks) {
    short8 afr[4], bfr[4];
#pragma unroll
    for (int mt = 0; mt < 4; ++mt)
      afr[mt] = *(const short8*)&h_lds[(wv * 64 + mt * 16 + lrow) * 72 + ks * 32 + lk * 8];
#pragma unroll
    for (int nt = 0; nt < 4; ++nt)
      bfr[nt] = *(const short8*)&w2_lds[(nt * 16 + lrow) * 72 + ks * 32 + lk * 8];
#pragma unroll
    for (int mt = 0; mt < 4; ++mt)
#pragma unroll
      for (int nt = 0; nt < 4; ++nt)
        acc[mt][nt] = __builtin_amdgcn_mfma_f32_16x16x32_bf16(afr[mt], bfr[nt], acc[mt][nt], 0, 0, 0);
  }
#pragma unroll
  for (int mt = 0; mt < 4; ++mt)
#pragma unroll
    for (int nt = 0; nt < 4; ++nt) {
      float bias = b2_lds[nt * 16 + lrow];
#pragma unroll
      for (int r = 0; r < 4; ++r) {
        float v = fmaxf(acc[mt][nt][r] + bias, 0.f);
        h_lds[(wv * 64 + mt * 16 + lk * 4 + r) * 72 + nt * 16 + lrow] = f2bf(v);
      }
    }

  floatx4 acc3[4][4];
#pragma unroll
  for (int mt = 0; mt < 4; ++mt)
#pragma unroll
    for (int nt = 0; nt < 4; ++nt) acc3[mt][nt] = (floatx4){0.f, 0.f, 0.f, 0.f};

#pragma unroll
  for (int ks = 0; ks < 2; ++ks) {
    short8 afr[4], bfr[4];
#pragma unroll
    for (int mt = 0; mt < 4; ++mt)
      afr[mt] = *(const short8*)&h_lds[(wv * 64 + mt * 16 + lrow) * 72 + ks * 32 + lk * 8];
#pragma unroll
    for (int nt = 0; nt < 4; ++nt)
      bfr[nt] = *(const short8*)&w3_lds[(nt * 16 + lrow) * 72 + ks * 32 + lk * 8];
#pragma unroll
    for (int mt = 0; mt < 4; ++mt)
#pragma unroll
      for (int nt = 0; nt < 4; ++nt)
        acc3[mt][nt] = __builtin_amdgcn_mfma_f32_16x16x32_bf16(afr[mt], bfr[nt], acc3[mt][nt], 0, 0, 0);
  }

  __syncthreads();
  unsigned* T = (unsigned*)h_lds;  // T[64 ch][132 u32]
#pragma unroll
  for (int mt = 0; mt < 4; ++mt)
#pragma unroll
    for (int nt = 0; nt < 4; ++nt) {
      float bias = b3_lds[nt * 16 + lrow];
      float v0 = fmaxf(acc3[mt][nt][0] + bias, 0.f);
      float v1 = fmaxf(acc3[mt][nt][1] + bias, 0.f);
      float v2 = fmaxf(acc3[mt][nt][2] + bias, 0.f);
      float v3 = fmaxf(acc3[mt][nt][3] + bias, 0.f);
      int ch = nt * 16 + lrow;
      int pp = (wv * 64 + mt * 16 + lk * 4) >> 1;
      T[ch * 132 + pp] = pk2(v0, v1);
      T[ch * 132 + pp + 1] = pk2(v2, v3);
    }
  __syncthreads();

  const int ch = t >> 2, q = t & 3;
  unsigned* wtu = (unsigned*)wt;
  size_t obase = ((size_t)(b * W_ + ch)) * (N_ / 2) + (n0 >> 1);
#pragma unroll
  for (int j = 0; j < 8; ++j) {
    int col = q * 4 + j * 16;
    uint4 vv = *(const uint4*)&T[ch * 132 + col];
    *(uint4*)&wtu[obase + col] = vv;
  }
}

// ---------------- K2: slab[ks][b][c*64+w] (f32) = sum_{k-chunk} feat[b][c][k]/N * wt[b][w][k] ----------------
// 1024 blocks = (ks*8 + ct)*32 + b; 4 waves; tile 32c x 64w, K-chunk 1024, step 128.
// global_load_lds staging (queue in TA, not VGPRs); XOR granule swizzle on both sides.
__global__ __launch_bounds__(256) void k2_agg(const float* __restrict__ feature,
                                              const ushort* __restrict__ wt,
                                              float* __restrict__ slabs) {
  __shared__ __align__(16) float A_lds[2][32 * 128];   // 16 KB x2, row = 512 B = 32 granules
  __shared__ __align__(16) ushort B_lds[2][64 * 128];  // 16 KB x2, row = 256 B = 16 granules

  const int t = threadIdx.x;
  const int wv = t >> 6, lane = t & 63;
  const int lrow = lane & 15, lk = lane >> 4;
  const int blk = blockIdx.x;
  const int b = blk & 31;
  const int ct = (blk >> 5) & 7;
  const int ks = blk >> 8;

  const float* fbase = feature + (size_t)(b * C_ + ct * 32) * N_ + ks * 1024;
  const ushort* wbase = wt + (size_t)(b * W_) * N_ + ks * 1024;

  // staging lane geometry (constant across steps)
  const int rowA = (lane >> 5);            // + 2*jA
  const int colA = (lane & 31);            // granule within A row (of 32)
  const int rowB = (lane >> 4);            // + 4*jB
  const int colB = (lane & 15);            // granule within B row (of 16)

#define STAGE(buf, step)                                                          \
  do {                                                                            \
    _Pragma("unroll")                                                             \
    for (int q = 0; q < 4; ++q) {                                                 \
      int jA = wv * 4 + q;                                                        \
      int ra = 2 * jA + rowA;                                                     \
      int ga = colA ^ (ra & 7); /* inverse-swizzled source granule */             \
      GLOAD_LDS16(fbase + (size_t)ra * N_ + (step) * 128 + ga * 4,                \
                  &A_lds[buf][jA * 256 + lane * 4]);                              \
      int jB = wv * 4 + q;                                                        \
      int rb = 4 * jB + rowB;                                                     \
      int gb = colB ^ (rb & 7);                                                   \
      GLOAD_LDS16(wbase + (size_t)rb * N_ + (step) * 128 + gb * 8,                \
                  &B_lds[buf][jB * 512 + lane * 8]);                              \
    }                                                                             \
  } while (0)

  const int cg = wv >> 1, wg = wv & 1;     // wave quadrant: c-half x w-half
  const int r_c = cg * 16 + lrow;
  const int eA = r_c & 7;
  const float* arow = &A_lds[0][r_c * 128];
  const int r_w0 = wg * 32 + lrow;         // wt2=0 row; wt2=1 adds 16
  const int eB0 = r_w0 & 7, eB1 = (r_w0 + 16) & 7;

  floatx4 acc[2];
  acc[0] = (floatx4){0.f, 0.f, 0.f, 0.f};
  acc[1] = (floatx4){0.f, 0.f, 0.f, 0.f};

  STAGE(0, 0);
  __syncthreads();

  for (int st = 0; st < 8; ++st) {
    const int cur = st & 1;
    if (st < 7) STAGE(cur ^ 1, st + 1);

    const float* ar = arow + cur * (32 * 128) * 0 + (size_t)cur * 0;  // (see below)
    // NOTE: arow points into A_lds[0]; A_lds[1] is +32*128 floats.
    const float* abuf = &A_lds[cur][r_c * 128];
    const ushort* bbuf0 = &B_lds[cur][r_w0 * 128];
    const ushort* bbuf1 = &B_lds[cur][(r_w0 + 16) * 128];
    (void)ar;

#pragma unroll
    for (int ksl = 0; ksl < 4; ++ksl) {
      const int p = ksl * 8 + lk * 2;      // even granule pair p, p+1
      float4 fa = *(const float4*)&abuf[((p) ^ eA) * 4];
      float4 fb = *(const float4*)&abuf[((p + 1) ^ eA) * 4];
      union { unsigned u[4]; short8 s8; } pa;
      pa.u[0] = pk2(fa.x, fa.y);
      pa.u[1] = pk2(fa.z, fa.w);
      pa.u[2] = pk2(fb.x, fb.y);
      pa.u[3] = pk2(fb.z, fb.w);
      const int g = ksl * 4 + lk;
      short8 b0 = *(const short8*)&bbuf0[(g ^ eB0) * 8];
      short8 b1 = *(const short8*)&bbuf1[(g ^ eB1) * 8];
      acc[0] = __builtin_amdgcn_mfma_f32_16x16x32_bf16(pa.s8, b0, acc[0], 0, 0, 0);
      acc[1] = __builtin_amdgcn_mfma_f32_16x16x32_bf16(pa.s8, b1, acc[1], 0, 0, 0);
    }
    __syncthreads();
  }
#undef STAGE

  // D: row = c-frag row = lk*4+r, col = w = lrow
  const float sc = 1.f / 4096.f;
  float* slab = slabs + ((size_t)(ks * B_ + b)) * 16384;
#pragma unroll
  for (int wt2 = 0; wt2 < 2; ++wt2)
#pragma unroll
    for (int r = 0; r < 4; ++r) {
      int c = ct * 32 + cg * 16 + lk * 4 + r;
      int w = wg * 32 + wt2 * 16 + lrow;
      slab[c * 64 + w] = acc[wt2][r] * sc;
    }
}

// ---------------- K2b: aggB[b][k=cw] (bf16) = sum_ks slab[ks][b][cw] ----------------
__global__ __launch_bounds__(256) void k2b_reduce(const float* __restrict__ slabs,
                                                  ushort* __restrict__ aggB) {
  const int t = threadIdx.x;
  const int b = blockIdx.x >> 3;
  const int idx = (blockIdx.x & 7) * 2048 + t * 8;

  float s[8] = {0.f, 0.f, 0.f, 0.f, 0.f, 0.f, 0.f, 0.f};
#pragma unroll
  for (int ks = 0; ks < 4; ++ks) {
    const float* p = slabs + ((size_t)(ks * B_ + b)) * 16384 + idx;
    float4 x0 = *(const float4*)p;
    float4 x1 = *(const float4*)(p + 4);
    s[0] += x0.x; s[1] += x0.y; s[2] += x0.z; s[3] += x0.w;
    s[4] += x1.x; s[5] += x1.y; s[6] += x1.z; s[7] += x1.w;
  }
  uint4 o;
  o.x = pk2(s[0], s[1]); o.y = pk2(s[2], s[3]);
  o.z = pk2(s[4], s[5]); o.w = pk2(s[6], s[7]);
  *(uint4*)&aggB[(size_t)b * 16384 + idx] = o;
}

// ---------------- K3: part[kb][o*32+b] = sum_{k-chunk} wf[o][k] * aggB[b][k]  (MFMA) ----------------
__global__ __launch_bounds__(256) void k3_final(const float* __restrict__ wf,
                                                const ushort* __restrict__ aggB,
                                                float* __restrict__ part) {
  const int t = threadIdx.x;
  const int wv = t >> 6, lane = t & 63;
  const int lrow = lane & 15, lk = lane >> 4;
  const int ot = blockIdx.x >> 6;
  const int kb = blockIdx.x & 63;
  const int o0 = ot * 64 + wv * 16;
  const int k0 = kb * 256;

  const float* wp = wf + (size_t)(o0 + lrow) * 16384 + k0 + lk * 8;
  const ushort* a0 = aggB + (size_t)lrow * 16384 + k0 + lk * 8;
  const ushort* a1 = a0 + (size_t)16 * 16384;

  floatx4 acc0 = {0.f, 0.f, 0.f, 0.f}, acc1 = {0.f, 0.f, 0.f, 0.f};
#pragma unroll
  for (int s = 0; s < 8; ++s) {
    float4 f0 = *(const float4*)(wp + s * 32);
    float4 f1 = *(const float4*)(wp + s * 32 + 4);
    short8 b0 = *(const short8*)(a0 + s * 32);
    short8 b1 = *(const short8*)(a1 + s * 32);
    union { unsigned u[4]; short8 s8; } pa;
    pa.u[0] = pk2(f0.x, f0.y);
    pa.u[1] = pk2(f0.z, f0.w);
    pa.u[2] = pk2(f1.x, f1.y);
    pa.u[3] = pk2(f1.z, f1.w);
    acc0 = __builtin_amdgcn_mfma_f32_16x16x32_bf16(pa.s8, b0, acc0, 0, 0, 0);
    acc1 = __builtin_amdgcn_mfma_f32_16x16x32_bf16(pa.s8, b1, acc1, 0, 0, 0);
  }

  float* dst = part + (size_t)kb * 16384;
#pragma unroll
  for (int r = 0; r < 4; ++r) {
    int o = o0 + lk * 4 + r;
    dst[o * 32 + lrow] = acc0[r];
    dst[o * 32 + 16 + lrow] = acc1[r];
  }
}

// ---------------- K4: reduce partials + final BN + ReLU ----------------
__global__ void k4_finalize(const float* __restrict__ bf, const float* __restrict__ gf,
                            const float* __restrict__ bef, const float* __restrict__ mf,
                            const float* __restrict__ vf, const float* __restrict__ part,
                            float* __restrict__ out) {
  int i = blockIdx.x * 256 + threadIdx.x;  // 0..16383
  int o = i >> 5, b = i & 31;
  float v = 0.f;
#pragma unroll
  for (int kb = 0; kb < 64; ++kb) v += part[(size_t)kb * 16384 + i];
  float s = gf[o] * rsqrtf(vf[o] + EPS_);
  float r = (v + bf[o] - mf[o]) * s + bef[o];
  out[b * OUT_ + o] = fmaxf(r, 0.f);
}

extern "C" void kernel_launch(void* const* d_in, const int* in_sizes, int n_in,
                              void* d_out, int out_size, void* d_ws, size_t ws_size,
                              hipStream_t stream) {
  const float* xyz     = (const float*)d_in[0];
  const float* feature = (const float*)d_in[1];
  const float* w1 = (const float*)d_in[3];
  const float* b1 = (const float*)d_in[4];
  const float* g1 = (const float*)d_in[5];
  const float* be1 = (const float*)d_in[6];
  const float* m1 = (const float*)d_in[7];
  const float* v1 = (const float*)d_in[8];
  const float* w2 = (const float*)d_in[9];
  const float* b2 = (const float*)d_in[10];
  const float* g2 = (const float*)d_in[11];
  const float* be2 = (const float*)d_in[12];
  const float* m2 = (const float*)d_in[13];
  const float* v2 = (const float*)d_in[14];
  const float* w3 = (const float*)d_in[15];
  const float* b3 = (const float*)d_in[16];
  const float* g3 = (const float*)d_in[17];
  const float* be3 = (const float*)d_in[18];
  const float* m3 = (const float*)d_in[19];
  const float* v3 = (const float*)d_in[20];
  const float* wf = (const float*)d_in[21];
  const float* bf = (const float*)d_in[22];
  const float* gf = (const float*)d_in[23];
  const float* bef = (const float*)d_in[24];
  const float* mf = (const float*)d_in[25];
  const float* vf = (const float*)d_in[26];

  char* ws = (char*)d_ws;
  if (ws_size < (size_t)WS_NEEDED) return;
  ushort* wt    = (ushort*)(ws + WT_OFF);
  float*  slabs = (float*)(ws + SLABF_OFF);
  ushort* aggB  = (ushort*)(ws + AGGB_OFF);
  float*  part  = (float*)(ws + PART_OFF);

  k1_weightnet<<<512, 256, 0, stream>>>(xyz,
                                        w1, b1, g1, be1, m1, v1,
                                        w2, b2, g2, be2, m2, v2,
                                        w3, b3, g3, be3, m3, v3, wt);
  k2_agg<<<1024, 256, 0, stream>>>(feature, wt, slabs);
  k2b_reduce<<<256, 256, 0, stream>>>(slabs, aggB);
  k3_final<<<512, 256, 0, stream>>>(wf, aggB, part);
  k4_finalize<<<64, 256, 0, stream>>>(bf, gf, bef, mf, vf, part, (float*)d_out);
}

// Round 7
// 74.378 us; speedup vs baseline: 1.1334x; 1.0088x over previous
//
#include <hip/hip_runtime.h>
#include <hip/hip_bf16.h>

#define B_ 32
#define N_ 4096
#define C_ 256
#define W_ 64
#define OUT_ 512
#define EPS_ 1e-5f

typedef __attribute__((ext_vector_type(8))) short short8;
typedef __attribute__((ext_vector_type(4))) float floatx4;

// workspace layout (bytes)
#define WT_OFF     0                    // wt bf16 [b][w][n] = 16 MB
#define SLABF_OFF  16777216             // 4 slabs f32 [ks][b][c*64+w] = 8 MB
#define AGGB_OFF   25165824             // aggB bf16 [b][k=c*64+w] = 1 MB
#define PART_OFF   26214400             // k3 partials f32 [kb<64][o*32+b] = 4 MB
#define WS_NEEDED  30408704

#define GLOAD_LDS16(g, l)                                                  \
  __builtin_amdgcn_global_load_lds(                                        \
      (const __attribute__((address_space(1))) void*)(g),                  \
      (__attribute__((address_space(3))) void*)(l), 16, 0, 0)

__device__ __forceinline__ ushort f2bf(float f) {
  unsigned u = __builtin_bit_cast(unsigned, f);
  unsigned r = (u + 0x7fffu + ((u >> 16) & 1u)) >> 16;  // RTNE
  return (ushort)r;
}
__device__ __forceinline__ unsigned pk2(float a, float b) {
  return (unsigned)f2bf(a) | ((unsigned)f2bf(b) << 16);
}

// ---------------- K1: fuse BN + WeightNet (layer1 scalar, layers 2/3 MFMA) ----------------
__global__ __launch_bounds__(256) void k1_weightnet(
    const float* __restrict__ xyz,
    const float* __restrict__ w1, const float* __restrict__ b1,
    const float* __restrict__ g1, const float* __restrict__ be1,
    const float* __restrict__ m1, const float* __restrict__ v1,
    const float* __restrict__ w2, const float* __restrict__ b2,
    const float* __restrict__ g2, const float* __restrict__ be2,
    const float* __restrict__ m2, const float* __restrict__ v2,
    const float* __restrict__ w3, const float* __restrict__ b3,
    const float* __restrict__ g3, const float* __restrict__ be3,
    const float* __restrict__ m3, const float* __restrict__ v3,
    ushort* __restrict__ wt) {
  __shared__ __align__(16) ushort h_lds[256 * 72];   // reused as T[64][132] u32
  __shared__ __align__(16) ushort w2_lds[64 * 72];
  __shared__ __align__(16) ushort w3_lds[64 * 72];
  __shared__ float w1l[192];
  __shared__ float b1l[64];
  __shared__ float b2_lds[64];
  __shared__ float b3_lds[64];

  const int t = threadIdx.x;
  const int blk = blockIdx.x;
  const int b = blk >> 4;
  const int n0 = (blk & 15) << 8;

  if (t < 64) {
    float s1 = g1[t] * rsqrtf(v1[t] + EPS_);
#pragma unroll
    for (int j = 0; j < 3; ++j) w1l[t * 3 + j] = w1[t * 3 + j] * s1;
    b1l[t] = (b1[t] - m1[t]) * s1 + be1[t];

    float s2 = g2[t] * rsqrtf(v2[t] + EPS_);
    unsigned* w2row = (unsigned*)&w2_lds[t * 72];
#pragma unroll
    for (int q = 0; q < 16; ++q) {
      float4 v = *(const float4*)&w2[t * 64 + q * 4];
      w2row[q * 2] = pk2(v.x * s2, v.y * s2);
      w2row[q * 2 + 1] = pk2(v.z * s2, v.w * s2);
    }
    w2row[32] = 0; w2row[33] = 0; w2row[34] = 0; w2row[35] = 0;
    b2_lds[t] = (b2[t] - m2[t]) * s2 + be2[t];

    float s3 = g3[t] * rsqrtf(v3[t] + EPS_);
    unsigned* w3row = (unsigned*)&w3_lds[t * 72];
#pragma unroll
    for (int q = 0; q < 16; ++q) {
      float4 v = *(const float4*)&w3[t * 64 + q * 4];
      w3row[q * 2] = pk2(v.x * s3, v.y * s3);
      w3row[q * 2 + 1] = pk2(v.z * s3, v.w * s3);
    }
    w3row[32] = 0; w3row[33] = 0; w3row[34] = 0; w3row[35] = 0;
    b3_lds[t] = (b3[t] - m3[t]) * s3 + be3[t];
  }
  __syncthreads();

  const int n = n0 + t;
  const float* xp = xyz + ((size_t)b * N_ + n) * 3;
  float x0 = xp[0], x1 = xp[1], x2 = xp[2];
  unsigned* hrow = (unsigned*)&h_lds[t * 72];
#pragma unroll 4
  for (int cp = 0; cp < 32; ++cp) {
    int c0 = cp * 2, c1 = cp * 2 + 1;
    float a0 = fmaxf(b1l[c0] + w1l[c0 * 3] * x0 + w1l[c0 * 3 + 1] * x1 + w1l[c0 * 3 + 2] * x2, 0.f);
    float a1 = fmaxf(b1l[c1] + w1l[c1 * 3] * x0 + w1l[c1 * 3 + 1] * x1 + w1l[c1 * 3 + 2] * x2, 0.f);
    hrow[cp] = pk2(a0, a1);
  }
  __syncthreads();

  const int wv = t >> 6, lane = t & 63;
  const int lrow = lane & 15, lk = lane >> 4;

  floatx4 acc[4][4];
#pragma unroll
  for (int mt = 0; mt < 4; ++mt)
#pragma unroll
    for (int nt = 0; nt < 4; ++nt) acc[mt][nt] = (floatx4){0.f, 0.f, 0.f, 0.f};

#pragma unroll
  for (int ks = 0; ks < 2; ++ks) {
    short8 afr[4], bfr[4];
#pragma unroll
    for (int mt = 0; mt < 4; ++mt)
      afr[mt] = *(const short8*)&h_lds[(wv * 64 + mt * 16 + lrow) * 72 + ks * 32 + lk * 8];
#pragma unroll
    for (int nt = 0; nt < 4; ++nt)
      bfr[nt] = *(const short8*)&w2_lds[(nt * 16 + lrow) * 72 + ks * 32 + lk * 8];
#pragma unroll
    for (int mt = 0; mt < 4; ++mt)
#pragma unroll
      for (int nt = 0; nt < 4; ++nt)
        acc[mt][nt] = __builtin_amdgcn_mfma_f32_16x16x32_bf16(afr[mt], bfr[nt], acc[mt][nt], 0, 0, 0);
  }
#pragma unroll
  for (int mt = 0; mt < 4; ++mt)
#pragma unroll
    for (int nt = 0; nt < 4; ++nt) {
      float bias = b2_lds[nt * 16 + lrow];
#pragma unroll
      for (int r = 0; r < 4; ++r) {
        float v = fmaxf(acc[mt][nt][r] + bias, 0.f);
        h_lds[(wv * 64 + mt * 16 + lk * 4 + r) * 72 + nt * 16 + lrow] = f2bf(v);
      }
    }

  floatx4 acc3[4][4];
#pragma unroll
  for (int mt = 0; mt < 4; ++mt)
#pragma unroll
    for (int nt = 0; nt < 4; ++nt) acc3[mt][nt] = (floatx4){0.f, 0.f, 0.f, 0.f};

#pragma unroll
  for (int ks = 0; ks < 2; ++ks) {
    short8 afr[4], bfr[4];
#pragma unroll
    for (int mt = 0; mt < 4; ++mt)
      afr[mt] = *(const short8*)&h_lds[(wv * 64 + mt * 16 + lrow) * 72 + ks * 32 + lk * 8];
#pragma unroll
    for (int nt = 0; nt < 4; ++nt)
      bfr[nt] = *(const short8*)&w3_lds[(nt * 16 + lrow) * 72 + ks * 32 + lk * 8];
#pragma unroll
    for (int mt = 0; mt < 4; ++mt)
#pragma unroll
      for (int nt = 0; nt < 4; ++nt)
        acc3[mt][nt] = __builtin_amdgcn_mfma_f32_16x16x32_bf16(afr[mt], bfr[nt], acc3[mt][nt], 0, 0, 0);
  }

  __syncthreads();
  unsigned* T = (unsigned*)h_lds;  // T[64 ch][132 u32]
#pragma unroll
  for (int mt = 0; mt < 4; ++mt)
#pragma unroll
    for (int nt = 0; nt < 4; ++nt) {
      float bias = b3_lds[nt * 16 + lrow];
      float v0 = fmaxf(acc3[mt][nt][0] + bias, 0.f);
      float v1 = fmaxf(acc3[mt][nt][1] + bias, 0.f);
      float v2 = fmaxf(acc3[mt][nt][2] + bias, 0.f);
      float v3 = fmaxf(acc3[mt][nt][3] + bias, 0.f);
      int ch = nt * 16 + lrow;
      int pp = (wv * 64 + mt * 16 + lk * 4) >> 1;
      T[ch * 132 + pp] = pk2(v0, v1);
      T[ch * 132 + pp + 1] = pk2(v2, v3);
    }
  __syncthreads();

  const int ch = t >> 2, q = t & 3;
  unsigned* wtu = (unsigned*)wt;
  size_t obase = ((size_t)(b * W_ + ch)) * (N_ / 2) + (n0 >> 1);
#pragma unroll
  for (int j = 0; j < 8; ++j) {
    int col = q * 4 + j * 16;
    uint4 vv = *(const uint4*)&T[ch * 132 + col];
    *(uint4*)&wtu[obase + col] = vv;
  }
}

// ---------------- K2: slab[ks][b][c*64+w] (f32) = sum_{k-chunk} feat[b][c][k]/N * wt[b][w][k] ----------------
// 1024 blocks = (ks*8 + ct)*32 + b; 4 waves; tile 32c x 64w, K-chunk 1024, step 128.
// global_load_lds staging + counted-vmcnt 2-phase pipeline (T4): loads stay in
// flight across the barrier; never drain vmcnt to 0 in the main loop.
__global__ __launch_bounds__(256) void k2_agg(const float* __restrict__ feature,
                                              const ushort* __restrict__ wt,
                                              float* __restrict__ slabs) {
  __shared__ __align__(16) float A_lds[2][32 * 128];   // 16 KB x2, row = 512 B = 32 granules
  __shared__ __align__(16) ushort B_lds[2][64 * 128];  // 16 KB x2, row = 256 B = 16 granules

  const int t = threadIdx.x;
  const int wv = t >> 6, lane = t & 63;
  const int lrow = lane & 15, lk = lane >> 4;
  const int blk = blockIdx.x;
  const int b = blk & 31;
  const int ct = (blk >> 5) & 7;
  const int ks = blk >> 8;

  const float* fbase = feature + (size_t)(b * C_ + ct * 32) * N_ + ks * 1024;
  const ushort* wbase = wt + (size_t)(b * W_) * N_ + ks * 1024;

  // staging lane geometry (constant across steps)
  const int rowA = (lane >> 5);            // + 2*jA
  const int colA = (lane & 31);            // granule within A row (of 32)
  const int rowB = (lane >> 4);            // + 4*jB
  const int colB = (lane & 15);            // granule within B row (of 16)

  // 8 global_load_lds per wave per STAGE -> vmcnt(8) waits exactly the previous stage
#define STAGE(buf, step)                                                          \
  do {                                                                            \
    _Pragma("unroll")                                                             \
    for (int q = 0; q < 4; ++q) {                                                 \
      int jA = wv * 4 + q;                                                        \
      int ra = 2 * jA + rowA;                                                     \
      int ga = colA ^ (ra & 7); /* inverse-swizzled source granule */             \
      GLOAD_LDS16(fbase + (size_t)ra * N_ + (step) * 128 + ga * 4,                \
                  &A_lds[buf][jA * 256 + lane * 4]);                              \
      int jB = wv * 4 + q;                                                        \
      int rb = 4 * jB + rowB;                                                     \
      int gb = colB ^ (rb & 7);                                                   \
      GLOAD_LDS16(wbase + (size_t)rb * N_ + (step) * 128 + gb * 8,                \
                  &B_lds[buf][jB * 512 + lane * 8]);                              \
    }                                                                             \
  } while (0)

  const int cg = wv >> 1, wg = wv & 1;     // wave quadrant: c-half x w-half
  const int r_c = cg * 16 + lrow;
  const int eA = r_c & 7;
  const int r_w0 = wg * 32 + lrow;         // wt2=0 row; wt2=1 adds 16
  const int eB0 = r_w0 & 7, eB1 = (r_w0 + 16) & 7;

  floatx4 acc[2];
  acc[0] = (floatx4){0.f, 0.f, 0.f, 0.f};
  acc[1] = (floatx4){0.f, 0.f, 0.f, 0.f};

  auto compute = [&](int cur) {
    const float* abuf = &A_lds[cur][r_c * 128];
    const ushort* bbuf0 = &B_lds[cur][r_w0 * 128];
    const ushort* bbuf1 = &B_lds[cur][(r_w0 + 16) * 128];
#pragma unroll
    for (int ksl = 0; ksl < 4; ++ksl) {
      const int p = ksl * 8 + lk * 2;      // even granule pair p, p+1
      float4 fa = *(const float4*)&abuf[((p) ^ eA) * 4];
      float4 fb = *(const float4*)&abuf[((p + 1) ^ eA) * 4];
      union { unsigned u[4]; short8 s8; } pa;
      pa.u[0] = pk2(fa.x, fa.y);
      pa.u[1] = pk2(fa.z, fa.w);
      pa.u[2] = pk2(fb.x, fb.y);
      pa.u[3] = pk2(fb.z, fb.w);
      const int g = ksl * 4 + lk;
      short8 b0 = *(const short8*)&bbuf0[(g ^ eB0) * 8];
      short8 b1 = *(const short8*)&bbuf1[(g ^ eB1) * 8];
      acc[0] = __builtin_amdgcn_mfma_f32_16x16x32_bf16(pa.s8, b0, acc[0], 0, 0, 0);
      acc[1] = __builtin_amdgcn_mfma_f32_16x16x32_bf16(pa.s8, b1, acc[1], 0, 0, 0);
    }
  };

  STAGE(0, 0);
  for (int st = 0; st < 7; ++st) {
    STAGE((st + 1) & 1, st + 1);
    // wait only for the PREVIOUS stage's 8 loads; keep the 8 new ones in flight
    asm volatile("s_waitcnt vmcnt(8)\n\ts_barrier" ::: "memory");
    compute(st & 1);
    // write-after-read protection before next iteration's STAGE overwrites cur
    asm volatile("s_barrier" ::: "memory");
  }
  asm volatile("s_waitcnt vmcnt(0)\n\ts_barrier" ::: "memory");
  compute(1);
#undef STAGE

  // D: row = c-frag row = lk*4+r, col = w = lrow
  const float sc = 1.f / 4096.f;
  float* slab = slabs + ((size_t)(ks * B_ + b)) * 16384;
#pragma unroll
  for (int wt2 = 0; wt2 < 2; ++wt2)
#pragma unroll
    for (int r = 0; r < 4; ++r) {
      int c = ct * 32 + cg * 16 + lk * 4 + r;
      int w = wg * 32 + wt2 * 16 + lrow;
      slab[c * 64 + w] = acc[wt2][r] * sc;
    }
}

// ---------------- K2b: aggB[b][k=cw] (bf16) = sum_ks slab[ks][b][cw] ----------------
__global__ __launch_bounds__(256) void k2b_reduce(const float* __restrict__ slabs,
                                                  ushort* __restrict__ aggB) {
  const int t = threadIdx.x;
  const int b = blockIdx.x >> 3;
  const int idx = (blockIdx.x & 7) * 2048 + t * 8;

  float s[8] = {0.f, 0.f, 0.f, 0.f, 0.f, 0.f, 0.f, 0.f};
#pragma unroll
  for (int ks = 0; ks < 4; ++ks) {
    const float* p = slabs + ((size_t)(ks * B_ + b)) * 16384 + idx;
    float4 x0 = *(const float4*)p;
    float4 x1 = *(const float4*)(p + 4);
    s[0] += x0.x; s[1] += x0.y; s[2] += x0.z; s[3] += x0.w;
    s[4] += x1.x; s[5] += x1.y; s[6] += x1.z; s[7] += x1.w;
  }
  uint4 o;
  o.x = pk2(s[0], s[1]); o.y = pk2(s[2], s[3]);
  o.z = pk2(s[4], s[5]); o.w = pk2(s[6], s[7]);
  *(uint4*)&aggB[(size_t)b * 16384 + idx] = o;
}

// ---------------- K3: part[kb][o*32+b] = sum_{k-chunk} wf[o][k] * aggB[b][k]  (MFMA) ----------------
__global__ __launch_bounds__(256) void k3_final(const float* __restrict__ wf,
                                                const ushort* __restrict__ aggB,
                                                float* __restrict__ part) {
  const int t = threadIdx.x;
  const int wv = t >> 6, lane = t & 63;
  const int lrow = lane & 15, lk = lane >> 4;
  const int ot = blockIdx.x >> 6;
  const int kb = blockIdx.x & 63;
  const int o0 = ot * 64 + wv * 16;
  const int k0 = kb * 256;

  const float* wp = wf + (size_t)(o0 + lrow) * 16384 + k0 + lk * 8;
  const ushort* a0 = aggB + (size_t)lrow * 16384 + k0 + lk * 8;
  const ushort* a1 = a0 + (size_t)16 * 16384;

  floatx4 acc0 = {0.f, 0.f, 0.f, 0.f}, acc1 = {0.f, 0.f, 0.f, 0.f};
#pragma unroll
  for (int s = 0; s < 8; ++s) {
    float4 f0 = *(const float4*)(wp + s * 32);
    float4 f1 = *(const float4*)(wp + s * 32 + 4);
    short8 b0 = *(const short8*)(a0 + s * 32);
    short8 b1 = *(const short8*)(a1 + s * 32);
    union { unsigned u[4]; short8 s8; } pa;
    pa.u[0] = pk2(f0.x, f0.y);
    pa.u[1] = pk2(f0.z, f0.w);
    pa.u[2] = pk2(f1.x, f1.y);
    pa.u[3] = pk2(f1.z, f1.w);
    acc0 = __builtin_amdgcn_mfma_f32_16x16x32_bf16(pa.s8, b0, acc0, 0, 0, 0);
    acc1 = __builtin_amdgcn_mfma_f32_16x16x32_bf16(pa.s8, b1, acc1, 0, 0, 0);
  }

  float* dst = part + (size_t)kb * 16384;
#pragma unroll
  for (int r = 0; r < 4; ++r) {
    int o = o0 + lk * 4 + r;
    dst[o * 32 + lrow] = acc0[r];
    dst[o * 32 + 16 + lrow] = acc1[r];
  }
}

// ---------------- K4: reduce partials + final BN + ReLU ----------------
__global__ __launch_bounds__(64) void k4_finalize(
    const float* __restrict__ bf, const float* __restrict__ gf,
    const float* __restrict__ bef, const float* __restrict__ mf,
    const float* __restrict__ vf, const float* __restrict__ part,
    float* __restrict__ out) {
  int i = blockIdx.x * 64 + threadIdx.x;  // 0..16383
  int o = i >> 5, b = i & 31;
  float v = 0.f;
#pragma unroll
  for (int kb = 0; kb < 64; ++kb) v += part[(size_t)kb * 16384 + i];
  float s = gf[o] * rsqrtf(vf[o] + EPS_);
  float r = (v + bf[o] - mf[o]) * s + bef[o];
  out[b * OUT_ + o] = fmaxf(r, 0.f);
}

extern "C" void kernel_launch(void* const* d_in, const int* in_sizes, int n_in,
                              void* d_out, int out_size, void* d_ws, size_t ws_size,
                              hipStream_t stream) {
  const float* xyz     = (const float*)d_in[0];
  const float* feature = (const float*)d_in[1];
  const float* w1 = (const float*)d_in[3];
  const float* b1 = (const float*)d_in[4];
  const float* g1 = (const float*)d_in[5];
  const float* be1 = (const float*)d_in[6];
  const float* m1 = (const float*)d_in[7];
  const float* v1 = (const float*)d_in[8];
  const float* w2 = (const float*)d_in[9];
  const float* b2 = (const float*)d_in[10];
  const float* g2 = (const float*)d_in[11];
  const float* be2 = (const float*)d_in[12];
  const float* m2 = (const float*)d_in[13];
  const float* v2 = (const float*)d_in[14];
  const float* w3 = (const float*)d_in[15];
  const float* b3 = (const float*)d_in[16];
  const float* g3 = (const float*)d_in[17];
  const float* be3 = (const float*)d_in[18];
  const float* m3 = (const float*)d_in[19];
  const float* v3 = (const float*)d_in[20];
  const float* wf = (const float*)d_in[21];
  const float* bf = (const float*)d_in[22];
  const float* gf = (const float*)d_in[23];
  const float* bef = (const float*)d_in[24];
  const float* mf = (const float*)d_in[25];
  const float* vf = (const float*)d_in[26];

  char* ws = (char*)d_ws;
  if (ws_size < (size_t)WS_NEEDED) return;
  ushort* wt    = (ushort*)(ws + WT_OFF);
  float*  slabs = (float*)(ws + SLABF_OFF);
  ushort* aggB  = (ushort*)(ws + AGGB_OFF);
  float*  part  = (float*)(ws + PART_OFF);

  k1_weightnet<<<512, 256, 0, stream>>>(xyz,
                                        w1, b1, g1, be1, m1, v1,
                                        w2, b2, g2, be2, m2, v2,
                                        w3, b3, g3, be3, m3, v3, wt);
  k2_agg<<<1024, 256, 0, stream>>>(feature, wt, slabs);
  k2b_reduce<<<256, 256, 0, stream>>>(slabs, aggB);
  k3_final<<<512, 256, 0, stream>>>(wf, aggB, part);
  k4_finalize<<<256, 64, 0, stream>>>(bf, gf, bef, mf, vf, part, (float*)d_out);
}

// Round 8
// 61.224 us; speedup vs baseline: 1.3769x; 1.2149x over previous
//
#include <hip/hip_runtime.h>
#include <hip/hip_bf16.h>

#define B_ 32
#define N_ 4096
#define C_ 256
#define W_ 64
#define OUT_ 512
#define EPS_ 1e-5f

typedef __attribute__((ext_vector_type(8))) short short8;
typedef __attribute__((ext_vector_type(4))) float floatx4;

// workspace layout (bytes)
#define WT_OFF     0                    // wt bf16 [b][w][n] = 16 MB
#define AGGB_OFF   16777216             // aggB bf16 [b][k=c*64+w] = 1 MB
#define PART_OFF   17825792             // k3 partials f32 [kb<32][o*32+b] = 2 MB
#define WS_NEEDED  19922944

#define GLOAD_LDS16(g, l)                                                  \
  __builtin_amdgcn_global_load_lds(                                        \
      (const __attribute__((address_space(1))) void*)(g),                  \
      (__attribute__((address_space(3))) void*)(l), 16, 0, 0)

__device__ __forceinline__ ushort f2bf(float f) {
  unsigned u = __builtin_bit_cast(unsigned, f);
  unsigned r = (u + 0x7fffu + ((u >> 16) & 1u)) >> 16;  // RTNE
  return (ushort)r;
}
__device__ __forceinline__ unsigned pk2(float a, float b) {
  return (unsigned)f2bf(a) | ((unsigned)f2bf(b) << 16);
}

// ---------------- K1: fuse BN + WeightNet (layer1 scalar, layers 2/3 MFMA) ----------------
__global__ __launch_bounds__(256) void k1_weightnet(
    const float* __restrict__ xyz,
    const float* __restrict__ w1, const float* __restrict__ b1,
    const float* __restrict__ g1, const float* __restrict__ be1,
    const float* __restrict__ m1, const float* __restrict__ v1,
    const float* __restrict__ w2, const float* __restrict__ b2,
    const float* __restrict__ g2, const float* __restrict__ be2,
    const float* __restrict__ m2, const float* __restrict__ v2,
    const float* __restrict__ w3, const float* __restrict__ b3,
    const float* __restrict__ g3, const float* __restrict__ be3,
    const float* __restrict__ m3, const float* __restrict__ v3,
    ushort* __restrict__ wt) {
  __shared__ __align__(16) ushort h_lds[256 * 72];   // reused as T[64][132] u32
  __shared__ __align__(16) ushort w2_lds[64 * 72];
  __shared__ __align__(16) ushort w3_lds[64 * 72];
  __shared__ float w1l[192];
  __shared__ float b1l[64];
  __shared__ float b2_lds[64];
  __shared__ float b3_lds[64];

  const int t = threadIdx.x;
  const int blk = blockIdx.x;
  const int b = blk >> 4;
  const int n0 = (blk & 15) << 8;

  if (t < 64) {
    float s1 = g1[t] * rsqrtf(v1[t] + EPS_);
#pragma unroll
    for (int j = 0; j < 3; ++j) w1l[t * 3 + j] = w1[t * 3 + j] * s1;
    b1l[t] = (b1[t] - m1[t]) * s1 + be1[t];

    float s2 = g2[t] * rsqrtf(v2[t] + EPS_);
    unsigned* w2row = (unsigned*)&w2_lds[t * 72];
#pragma unroll
    for (int q = 0; q < 16; ++q) {
      float4 v = *(const float4*)&w2[t * 64 + q * 4];
      w2row[q * 2] = pk2(v.x * s2, v.y * s2);
      w2row[q * 2 + 1] = pk2(v.z * s2, v.w * s2);
    }
    w2row[32] = 0; w2row[33] = 0; w2row[34] = 0; w2row[35] = 0;
    b2_lds[t] = (b2[t] - m2[t]) * s2 + be2[t];

    float s3 = g3[t] * rsqrtf(v3[t] + EPS_);
    unsigned* w3row = (unsigned*)&w3_lds[t * 72];
#pragma unroll
    for (int q = 0; q < 16; ++q) {
      float4 v = *(const float4*)&w3[t * 64 + q * 4];
      w3row[q * 2] = pk2(v.x * s3, v.y * s3);
      w3row[q * 2 + 1] = pk2(v.z * s3, v.w * s3);
    }
    w3row[32] = 0; w3row[33] = 0; w3row[34] = 0; w3row[35] = 0;
    b3_lds[t] = (b3[t] - m3[t]) * s3 + be3[t];
  }
  __syncthreads();

  const int n = n0 + t;
  const float* xp = xyz + ((size_t)b * N_ + n) * 3;
  float x0 = xp[0], x1 = xp[1], x2 = xp[2];
  unsigned* hrow = (unsigned*)&h_lds[t * 72];
#pragma unroll 4
  for (int cp = 0; cp < 32; ++cp) {
    int c0 = cp * 2, c1 = cp * 2 + 1;
    float a0 = fmaxf(b1l[c0] + w1l[c0 * 3] * x0 + w1l[c0 * 3 + 1] * x1 + w1l[c0 * 3 + 2] * x2, 0.f);
    float a1 = fmaxf(b1l[c1] + w1l[c1 * 3] * x0 + w1l[c1 * 3 + 1] * x1 + w1l[c1 * 3 + 2] * x2, 0.f);
    hrow[cp] = pk2(a0, a1);
  }
  __syncthreads();

  const int wv = t >> 6, lane = t & 63;
  const int lrow = lane & 15, lk = lane >> 4;

  floatx4 acc[4][4];
#pragma unroll
  for (int mt = 0; mt < 4; ++mt)
#pragma unroll
    for (int nt = 0; nt < 4; ++nt) acc[mt][nt] = (floatx4){0.f, 0.f, 0.f, 0.f};

#pragma unroll
  for (int ks = 0; ks < 2; ++ks) {
    short8 afr[4], bfr[4];
#pragma unroll
    for (int mt = 0; mt < 4; ++mt)
      afr[mt] = *(const short8*)&h_lds[(wv * 64 + mt * 16 + lrow) * 72 + ks * 32 + lk * 8];
#pragma unroll
    for (int nt = 0; nt < 4; ++nt)
      bfr[nt] = *(const short8*)&w2_lds[(nt * 16 + lrow) * 72 + ks * 32 + lk * 8];
#pragma unroll
    for (int mt = 0; mt < 4; ++mt)
#pragma unroll
      for (int nt = 0; nt < 4; ++nt)
        acc[mt][nt] = __builtin_amdgcn_mfma_f32_16x16x32_bf16(afr[mt], bfr[nt], acc[mt][nt], 0, 0, 0);
  }
#pragma unroll
  for (int mt = 0; mt < 4; ++mt)
#pragma unroll
    for (int nt = 0; nt < 4; ++nt) {
      float bias = b2_lds[nt * 16 + lrow];
#pragma unroll
      for (int r = 0; r < 4; ++r) {
        float v = fmaxf(acc[mt][nt][r] + bias, 0.f);
        h_lds[(wv * 64 + mt * 16 + lk * 4 + r) * 72 + nt * 16 + lrow] = f2bf(v);
      }
    }

  floatx4 acc3[4][4];
#pragma unroll
  for (int mt = 0; mt < 4; ++mt)
#pragma unroll
    for (int nt = 0; nt < 4; ++nt) acc3[mt][nt] = (floatx4){0.f, 0.f, 0.f, 0.f};

#pragma unroll
  for (int ks = 0; ks < 2; ++ks) {
    short8 afr[4], bfr[4];
#pragma unroll
    for (int mt = 0; mt < 4; ++mt)
      afr[mt] = *(const short8*)&h_lds[(wv * 64 + mt * 16 + lrow) * 72 + ks * 32 + lk * 8];
#pragma unroll
    for (int nt = 0; nt < 4; ++nt)
      bfr[nt] = *(const short8*)&w3_lds[(nt * 16 + lrow) * 72 + ks * 32 + lk * 8];
#pragma unroll
    for (int mt = 0; mt < 4; ++mt)
#pragma unroll
      for (int nt = 0; nt < 4; ++nt)
        acc3[mt][nt] = __builtin_amdgcn_mfma_f32_16x16x32_bf16(afr[mt], bfr[nt], acc3[mt][nt], 0, 0, 0);
  }

  __syncthreads();
  unsigned* T = (unsigned*)h_lds;  // T[64 ch][132 u32]
#pragma unroll
  for (int mt = 0; mt < 4; ++mt)
#pragma unroll
    for (int nt = 0; nt < 4; ++nt) {
      float bias = b3_lds[nt * 16 + lrow];
      float v0 = fmaxf(acc3[mt][nt][0] + bias, 0.f);
      float v1 = fmaxf(acc3[mt][nt][1] + bias, 0.f);
      float v2 = fmaxf(acc3[mt][nt][2] + bias, 0.f);
      float v3 = fmaxf(acc3[mt][nt][3] + bias, 0.f);
      int ch = nt * 16 + lrow;
      int pp = (wv * 64 + mt * 16 + lk * 4) >> 1;
      T[ch * 132 + pp] = pk2(v0, v1);
      T[ch * 132 + pp + 1] = pk2(v2, v3);
    }
  __syncthreads();

  const int ch = t >> 2, q = t & 3;
  unsigned* wtu = (unsigned*)wt;
  size_t obase = ((size_t)(b * W_ + ch)) * (N_ / 2) + (n0 >> 1);
#pragma unroll
  for (int j = 0; j < 8; ++j) {
    int col = q * 4 + j * 16;
    uint4 vv = *(const uint4*)&T[ch * 132 + col];
    *(uint4*)&wtu[obase + col] = vv;
  }
}

// ---------------- K2: aggB[b][c*64+w] (bf16) = sum_n feat[b][c][n]/N * wt[b][w][n] ----------------
// 256 blocks = ct*32 + b (1 block/CU); 4 waves; tile 32c x 64w; full K=4096 in 32 steps.
// 3-deep global_load_lds pipeline, counted vmcnt (16 steady / 8 / 0 tail).
__global__ __launch_bounds__(256) void k2_agg(const float* __restrict__ feature,
                                              const ushort* __restrict__ wt,
                                              ushort* __restrict__ aggB) {
  __shared__ __align__(16) float A_lds[3][32 * 128];   // 48 KB
  __shared__ __align__(16) ushort B_lds[3][64 * 128];  // 48 KB

  const int t = threadIdx.x;
  const int wv = t >> 6, lane = t & 63;
  const int lrow = lane & 15, lk = lane >> 4;
  const int blk = blockIdx.x;
  const int b = blk & 31;
  const int ct = blk >> 5;     // 0..7; same-b blocks at stride 32 -> same XCD (wt L2 reuse)

  const float* fbase = feature + (size_t)(b * C_ + ct * 32) * N_;
  const ushort* wbase = wt + (size_t)(b * W_) * N_;

  const int rowA = (lane >> 5);            // + 2*j
  const int colA = (lane & 31);            // granule (16B) within A row (of 32)
  const int rowB = (lane >> 4);            // + 4*j
  const int colB = (lane & 15);            // granule within B row (of 16)

  // 8 global_load_lds per wave per STAGE
#define STAGE(buf, step)                                                          \
  do {                                                                            \
    _Pragma("unroll")                                                             \
    for (int q = 0; q < 4; ++q) {                                                 \
      int j = wv * 4 + q;                                                         \
      int ra = 2 * j + rowA;                                                      \
      int ga = colA ^ (ra & 7); /* inverse-swizzled source granule */             \
      GLOAD_LDS16(fbase + (size_t)ra * N_ + (step) * 128 + ga * 4,                \
                  &A_lds[buf][j * 256 + lane * 4]);                               \
      int rb = 4 * j + rowB;                                                      \
      int gb = colB ^ (rb & 7);                                                   \
      GLOAD_LDS16(wbase + (size_t)rb * N_ + (step) * 128 + gb * 8,                \
                  &B_lds[buf][j * 512 + lane * 8]);                               \
    }                                                                             \
  } while (0)

  const int cg = wv >> 1, wg = wv & 1;     // wave quadrant: c-half x w-half
  const int r_c = cg * 16 + lrow;
  const int eA = r_c & 7;
  const int r_w0 = wg * 32 + lrow;
  const int eB0 = r_w0 & 7, eB1 = (r_w0 + 16) & 7;

  floatx4 acc[2];
  acc[0] = (floatx4){0.f, 0.f, 0.f, 0.f};
  acc[1] = (floatx4){0.f, 0.f, 0.f, 0.f};

  auto compute = [&](int cur) {
    const float* abuf = &A_lds[cur][r_c * 128];
    const ushort* bbuf0 = &B_lds[cur][r_w0 * 128];
    const ushort* bbuf1 = &B_lds[cur][(r_w0 + 16) * 128];
#pragma unroll
    for (int ksl = 0; ksl < 4; ++ksl) {
      const int p = ksl * 8 + lk * 2;
      float4 fa = *(const float4*)&abuf[((p) ^ eA) * 4];
      float4 fb = *(const float4*)&abuf[((p + 1) ^ eA) * 4];
      union { unsigned u[4]; short8 s8; } pa;
      pa.u[0] = pk2(fa.x, fa.y);
      pa.u[1] = pk2(fa.z, fa.w);
      pa.u[2] = pk2(fb.x, fb.y);
      pa.u[3] = pk2(fb.z, fb.w);
      const int g = ksl * 4 + lk;
      short8 b0 = *(const short8*)&bbuf0[(g ^ eB0) * 8];
      short8 b1 = *(const short8*)&bbuf1[(g ^ eB1) * 8];
      acc[0] = __builtin_amdgcn_mfma_f32_16x16x32_bf16(pa.s8, b0, acc[0], 0, 0, 0);
      acc[1] = __builtin_amdgcn_mfma_f32_16x16x32_bf16(pa.s8, b1, acc[1], 0, 0, 0);
    }
  };

#define WAIT_BAR(n) asm volatile("s_waitcnt vmcnt(" #n ")\n\ts_barrier" ::: "memory")
#define BAR()       asm volatile("s_barrier" ::: "memory")

  STAGE(0, 0);
  STAGE(1, 1);
  // steps 0..29: compute buf st%3, prefetch step st+2 into buf (st+2)%3 (all static)
  for (int g = 0; g < 10; ++g) {
    STAGE(2, 3 * g + 2); WAIT_BAR(16); compute(0); BAR();
    STAGE(0, 3 * g + 3); WAIT_BAR(16); compute(1); BAR();
    STAGE(1, 3 * g + 4); WAIT_BAR(16); compute(2); BAR();
  }
  // tail: step 30 (buf 0), step 31 (buf 1)
  WAIT_BAR(8);  compute(0); BAR();
  WAIT_BAR(0);  compute(1);
#undef STAGE
#undef WAIT_BAR
#undef BAR

  // D: row = c-frag row = lk*4+r, col = w = lrow
  const float sc = 1.f / 4096.f;
  ushort* dst = aggB + (size_t)b * 16384;
#pragma unroll
  for (int wt2 = 0; wt2 < 2; ++wt2)
#pragma unroll
    for (int r = 0; r < 4; ++r) {
      int c = ct * 32 + cg * 16 + lk * 4 + r;
      int w = wg * 32 + wt2 * 16 + lrow;
      dst[c * 64 + w] = f2bf(acc[wt2][r] * sc);
    }
}

// ---------------- K3: part[kb][o*32+b] = sum_{k-chunk} wf[o][k] * aggB[b][k]  (MFMA) ----------------
// 256 blocks = 8 o-tiles x 32 k-splits, 4 waves; wave owns 16 o rows, all 32 b, K-chunk 512.
__global__ __launch_bounds__(256) void k3_final(const float* __restrict__ wf,
                                                const ushort* __restrict__ aggB,
                                                float* __restrict__ part) {
  const int t = threadIdx.x;
  const int wv = t >> 6, lane = t & 63;
  const int lrow = lane & 15, lk = lane >> 4;
  const int ot = blockIdx.x >> 5;
  const int kb = blockIdx.x & 31;
  const int o0 = ot * 64 + wv * 16;
  const int k0 = kb * 512;

  const float* wp = wf + (size_t)(o0 + lrow) * 16384 + k0 + lk * 8;
  const ushort* a0 = aggB + (size_t)lrow * 16384 + k0 + lk * 8;
  const ushort* a1 = a0 + (size_t)16 * 16384;

  floatx4 acc0 = {0.f, 0.f, 0.f, 0.f}, acc1 = {0.f, 0.f, 0.f, 0.f};
#pragma unroll 8
  for (int s = 0; s < 16; ++s) {
    float4 f0 = *(const float4*)(wp + s * 32);
    float4 f1 = *(const float4*)(wp + s * 32 + 4);
    short8 b0 = *(const short8*)(a0 + s * 32);
    short8 b1 = *(const short8*)(a1 + s * 32);
    union { unsigned u[4]; short8 s8; } pa;
    pa.u[0] = pk2(f0.x, f0.y);
    pa.u[1] = pk2(f0.z, f0.w);
    pa.u[2] = pk2(f1.x, f1.y);
    pa.u[3] = pk2(f1.z, f1.w);
    acc0 = __builtin_amdgcn_mfma_f32_16x16x32_bf16(pa.s8, b0, acc0, 0, 0, 0);
    acc1 = __builtin_amdgcn_mfma_f32_16x16x32_bf16(pa.s8, b1, acc1, 0, 0, 0);
  }

  float* dst = part + (size_t)kb * 16384;
#pragma unroll
  for (int r = 0; r < 4; ++r) {
    int o = o0 + lk * 4 + r;
    dst[o * 32 + lrow] = acc0[r];
    dst[o * 32 + 16 + lrow] = acc1[r];
  }
}

// ---------------- K4: reduce partials + final BN + ReLU ----------------
__global__ __launch_bounds__(64) void k4_finalize(
    const float* __restrict__ bf, const float* __restrict__ gf,
    const float* __restrict__ bef, const float* __restrict__ mf,
    const float* __restrict__ vf, const float* __restrict__ part,
    float* __restrict__ out) {
  int i = blockIdx.x * 64 + threadIdx.x;  // 0..16383
  int o = i >> 5, b = i & 31;
  float v = 0.f;
#pragma unroll
  for (int kb = 0; kb < 32; ++kb) v += part[(size_t)kb * 16384 + i];
  float s = gf[o] * rsqrtf(vf[o] + EPS_);
  float r = (v + bf[o] - mf[o]) * s + bef[o];
  out[b * OUT_ + o] = fmaxf(r, 0.f);
}

extern "C" void kernel_launch(void* const* d_in, const int* in_sizes, int n_in,
                              void* d_out, int out_size, void* d_ws, size_t ws_size,
                              hipStream_t stream) {
  const float* xyz     = (const float*)d_in[0];
  const float* feature = (const float*)d_in[1];
  const float* w1 = (const float*)d_in[3];
  const float* b1 = (const float*)d_in[4];
  const float* g1 = (const float*)d_in[5];
  const float* be1 = (const float*)d_in[6];
  const float* m1 = (const float*)d_in[7];
  const float* v1 = (const float*)d_in[8];
  const float* w2 = (const float*)d_in[9];
  const float* b2 = (const float*)d_in[10];
  const float* g2 = (const float*)d_in[11];
  const float* be2 = (const float*)d_in[12];
  const float* m2 = (const float*)d_in[13];
  const float* v2 = (const float*)d_in[14];
  const float* w3 = (const float*)d_in[15];
  const float* b3 = (const float*)d_in[16];
  const float* g3 = (const float*)d_in[17];
  const float* be3 = (const float*)d_in[18];
  const float* m3 = (const float*)d_in[19];
  const float* v3 = (const float*)d_in[20];
  const float* wf = (const float*)d_in[21];
  const float* bf = (const float*)d_in[22];
  const float* gf = (const float*)d_in[23];
  const float* bef = (const float*)d_in[24];
  const float* mf = (const float*)d_in[25];
  const float* vf = (const float*)d_in[26];

  char* ws = (char*)d_ws;
  if (ws_size < (size_t)WS_NEEDED) return;
  ushort* wt   = (ushort*)(ws + WT_OFF);
  ushort* aggB = (ushort*)(ws + AGGB_OFF);
  float*  part = (float*)(ws + PART_OFF);

  k1_weightnet<<<512, 256, 0, stream>>>(xyz,
                                        w1, b1, g1, be1, m1, v1,
                                        w2, b2, g2, be2, m2, v2,
                                        w3, b3, g3, be3, m3, v3, wt);
  k2_agg<<<256, 256, 0, stream>>>(feature, wt, aggB);
  k3_final<<<256, 256, 0, stream>>>(wf, aggB, part);
  k4_finalize<<<256, 64, 0, stream>>>(bf, gf, bef, mf, vf, part, (float*)d_out);
}